// Round 1
// baseline (4892.723 us; speedup 1.0000x reference)
//
#include <hip/hip_runtime.h>
#include <cstddef>

// ---------------------------------------------------------------------------
// SuperGlue-style matcher: kenc -> 18 GNN layers -> final proj -> scores ->
// log-optimal-transport (Sinkhorn, 100 iters). All fp32 (round 1: correctness
// first; threshold is 0.3075 absolute).
// ---------------------------------------------------------------------------

#define TPB 256

__device__ __forceinline__ float block_sum(float v, float* red) {
  int tid = threadIdx.x;
  red[tid] = v; __syncthreads();
#pragma unroll
  for (int off = 128; off > 0; off >>= 1) {
    if (tid < off) red[tid] += red[tid + off];
    __syncthreads();
  }
  float r = red[0];
  __syncthreads();
  return r;
}

__device__ __forceinline__ float block_max(float v, float* red) {
  int tid = threadIdx.x;
  red[tid] = v; __syncthreads();
#pragma unroll
  for (int off = 128; off > 0; off >>= 1) {
    if (tid < off) red[tid] = fmaxf(red[tid], red[tid + off]);
    __syncthreads();
  }
  float r = red[0];
  __syncthreads();
  return r;
}

// ---------------------------------------------------------------------------
// h0 build: h0[im][4][1024]; rows 0..2 = keypoint xyz, row 3 = scores
// ---------------------------------------------------------------------------
__global__ __launch_bounds__(TPB) void build_h0(const float* __restrict__ kp0,
                                                const float* __restrict__ kp1,
                                                const float* __restrict__ sc0,
                                                const float* __restrict__ sc1,
                                                float* __restrict__ h0) {
  int n = blockIdx.x * TPB + threadIdx.x;   // 0..1023
  int im = blockIdx.y;
  const float* kp = im ? kp1 : kp0;
  const float* sc = im ? sc1 : sc0;
  float* h = h0 + (size_t)im * 4096;
  h[n]        = kp[n * 3 + 0];
  h[1024 + n] = kp[n * 3 + 1];
  h[2048 + n] = kp[n * 3 + 2];
  h[3072 + n] = sc[n];
}

// ---------------------------------------------------------------------------
// kenc layer: out[o][n] = conv1 over C channels; optional inorm+relu; optional
// residual (descriptors). One WG per (out-channel, image); 4 positions/thread.
// ---------------------------------------------------------------------------
template<bool NORMRELU, bool RESID>
__global__ __launch_bounds__(TPB) void chanconv(const float* __restrict__ W,
                                                const float* __restrict__ bias,
                                                const float* __restrict__ in, long instride,
                                                const float* res0, const float* res1,
                                                float* __restrict__ out, long outstride, int C) {
  int o = blockIdx.x, im = blockIdx.y, tid = threadIdx.x;
  const float* inp = in + (long)im * instride;
  __shared__ float Ws[128];
  __shared__ float red[TPB];
  for (int c = tid; c < C; c += TPB) Ws[c] = W[(long)o * C + c];
  __syncthreads();
  float b = bias[o];
  float acc[4] = {b, b, b, b};
  for (int c = 0; c < C; ++c) {
    float w = Ws[c];
    const float* row = inp + (long)c * 1024;
#pragma unroll
    for (int r = 0; r < 4; ++r) acc[r] += w * row[tid + r * TPB];
  }
  float* orow = out + (long)im * outstride + (long)o * 1024;
  if (NORMRELU) {
    float s = acc[0] + acc[1] + acc[2] + acc[3];
    float mean = block_sum(s, red) * (1.f / 1024.f);
    float s2 = 0.f;
#pragma unroll
    for (int r = 0; r < 4; ++r) { float d = acc[r] - mean; s2 += d * d; }
    float var = block_sum(s2, red) * (1.f / 1024.f);
    float rstd = rsqrtf(var + 1e-5f);
#pragma unroll
    for (int r = 0; r < 4; ++r) {
      float y = (acc[r] - mean) * rstd;
      orow[tid + r * TPB] = fmaxf(y, 0.f);
    }
  } else {
    const float* res = im ? res1 : res0;
#pragma unroll
    for (int r = 0; r < 4; ++r) {
      float y = acc[r];
      if (RESID) y += res[(long)o * 1024 + tid + r * TPB];
      orow[tid + r * TPB] = y;
    }
  }
}

// ---------------------------------------------------------------------------
// Batched tiled GEMM.  C[M][N] = alpha * op(A)*op(B) + bias[m] + res[m][n]
//   AMODE 0: A[m][k] row-major (lda = row stride); AMODE 1: A[k][m] (lda = k stride)
//   BMODE 0: B[k][n] (ldb = k stride);             BMODE 1: B[n][k] (ldb = n stride)
//   BSPLIT: B row k<ksplit from B, else B2 (concat along K)
//   BNORM : B element -> relu((x - mu[k]) * rs[k])   (fused inorm+relu)
//   out2  : optional transposed secondary store (ldc2)
// Tiles 64x64x16, 256 threads, 4x4 microtile.
// ---------------------------------------------------------------------------
struct GB {
  const float* A; const float* B; const float* B2; float* C;
  const float* bias; const float* res; float* out2;
  const float* mu; const float* rs;
};
struct GB8 { GB g[8]; };

#define BM 64
#define BN 64
#define BK 16

template<int AMODE, int BMODE, bool BSPLIT, bool BNORM>
__global__ __launch_bounds__(TPB) void gemm(GB8 gbs, int M, int N, int K,
                                            int lda, int ldb, int ldc, int ldc2,
                                            float alpha, int ksplit) {
  GB g = gbs.g[blockIdx.z];
  int m0 = blockIdx.y * BM, n0 = blockIdx.x * BN;
  __shared__ float As[BK][BM + 4];
  __shared__ float Bs[BK][BN + 4];
  float acc[4][4] = {};
  int tid = threadIdx.x;
  int ty = tid >> 4, tx = tid & 15;

  for (int k0 = 0; k0 < K; k0 += BK) {
#pragma unroll
    for (int r = 0; r < (BM * BK) / TPB; ++r) {
      int idx = tid + r * TPB;
      if (AMODE == 0) {
        int mm = idx >> 4, kk = idx & 15;
        As[kk][mm] = g.A[(long)(m0 + mm) * lda + k0 + kk];
      } else {
        int kk = idx >> 6, mm = idx & 63;
        As[kk][mm] = g.A[(long)(k0 + kk) * lda + m0 + mm];
      }
    }
#pragma unroll
    for (int r = 0; r < (BN * BK) / TPB; ++r) {
      int idx = tid + r * TPB;
      float val;
      int kk, nn;
      if (BMODE == 0) {
        kk = idx >> 6; nn = idx & 63;
        int kg = k0 + kk;
        const float* bp;
        if (BSPLIT) bp = (kg < ksplit) ? (g.B + (long)kg * ldb)
                                       : (g.B2 + (long)(kg - ksplit) * ldb);
        else bp = g.B + (long)kg * ldb;
        val = bp[n0 + nn];
        if (BNORM) {
          val = (val - g.mu[kg]) * g.rs[kg];
          val = fmaxf(val, 0.f);
        }
      } else {
        nn = idx >> 4; kk = idx & 15;
        val = g.B[(long)(n0 + nn) * ldb + k0 + kk];
      }
      Bs[kk][nn] = val;
    }
    __syncthreads();
#pragma unroll
    for (int kk = 0; kk < BK; ++kk) {
      float a[4], b[4];
#pragma unroll
      for (int i = 0; i < 4; ++i) a[i] = As[kk][ty * 4 + i];
#pragma unroll
      for (int j = 0; j < 4; ++j) b[j] = Bs[kk][tx * 4 + j];
#pragma unroll
      for (int i = 0; i < 4; ++i)
#pragma unroll
        for (int j = 0; j < 4; ++j) acc[i][j] += a[i] * b[j];
    }
    __syncthreads();
  }

#pragma unroll
  for (int i = 0; i < 4; ++i) {
    int m = m0 + ty * 4 + i;
    float bi = g.bias ? g.bias[m] : 0.f;
#pragma unroll
    for (int j = 0; j < 4; ++j) {
      int n = n0 + tx * 4 + j;
      float v = acc[i][j] * alpha + bi;
      if (g.res) v += g.res[(long)m * ldc + n];
      g.C[(long)m * ldc + n] = v;
      if (g.out2) g.out2[(long)n * ldc2 + m] = v;
    }
  }
}

// ---------------------------------------------------------------------------
// Row softmax over 1024 elements; one WG per row.
// ---------------------------------------------------------------------------
__global__ __launch_bounds__(TPB) void softmax_rows(float* __restrict__ S) {
  long row = blockIdx.x;
  float* p = S + row * 1024;
  int tid = threadIdx.x;
  __shared__ float red[TPB];
  float x[4];
#pragma unroll
  for (int r = 0; r < 4; ++r) x[r] = p[tid + r * TPB];
  float m = fmaxf(fmaxf(x[0], x[1]), fmaxf(x[2], x[3]));
  float M = block_max(m, red);
  float e[4]; float s = 0.f;
#pragma unroll
  for (int r = 0; r < 4; ++r) { e[r] = __expf(x[r] - M); s += e[r]; }
  float tot = block_sum(s, red);
  float inv = 1.f / tot;
#pragma unroll
  for (int r = 0; r < 4; ++r) p[tid + r * TPB] = e[r] * inv;
}

// ---------------------------------------------------------------------------
// Per-row mean / rsqrt(var+eps) over 1024 elements (for mlp0 instance norm).
// ---------------------------------------------------------------------------
__global__ __launch_bounds__(TPB) void rowstats(const float* __restrict__ t,
                                                float* __restrict__ mu,
                                                float* __restrict__ rs) {
  int r = blockIdx.x, tid = threadIdx.x;
  const float* row = t + (long)r * 1024;
  __shared__ float red[TPB];
  float x[4];
#pragma unroll
  for (int k = 0; k < 4; ++k) x[k] = row[tid + k * TPB];
  float s = x[0] + x[1] + x[2] + x[3];
  float mean = block_sum(s, red) * (1.f / 1024.f);
  float s2 = 0.f;
#pragma unroll
  for (int k = 0; k < 4; ++k) { float d = x[k] - mean; s2 += d * d; }
  float var = block_sum(s2, red) * (1.f / 1024.f);
  if (tid == 0) { mu[r] = mean; rs[r] = rsqrtf(var + 1e-5f); }
}

// ---------------------------------------------------------------------------
// Sinkhorn pieces
// ---------------------------------------------------------------------------
#define NORMC  (-7.62461899f)   /* -log(2048) */
#define LOGN   (6.93147181f)    /* log(1024)  */
#define LOG_MN (7.62461899f)    /* log(2048)  */

__global__ __launch_bounds__(TPB) void fill_bins(float* __restrict__ Z,
                                                 float* __restrict__ Zt,
                                                 const float* __restrict__ alpha_p) {
  float a = *alpha_p;
  int t = blockIdx.x * TPB + threadIdx.x;
  if (t <= 1024) {
    Z[(long)t * 1025 + 1024] = a;
    Z[(long)1024 * 1025 + t] = a;
    Zt[(long)t * 1025 + 1024] = a;
    Zt[(long)1024 * 1025 + t] = a;
  }
}

__global__ __launch_bounds__(TPB) void vinit(float* __restrict__ v) {
  int t = blockIdx.x * TPB + threadIdx.x;
  if (t < 1025) v[t] = 0.f;
}

// out[i] = mu_i - logsumexp_j( Zm[i][j] + w[j] ),  Zm row-major ld=1025
__global__ __launch_bounds__(TPB) void sink_step(const float* __restrict__ Zm,
                                                 const float* __restrict__ w,
                                                 float* __restrict__ out) {
  int i = blockIdx.x;
  int tid = threadIdx.x;
  const float* row = Zm + (long)i * 1025;
  float m = -1e30f, s = 0.f;
  for (int j = tid; j < 1025; j += TPB) {
    float val = row[j] + w[j];
    if (val > m) { s = s * __expf(m - val) + 1.f; m = val; }
    else s += __expf(val - m);
  }
  __shared__ float sm[TPB], ss[TPB];
  sm[tid] = m; ss[tid] = s;
  __syncthreads();
#pragma unroll
  for (int off = 128; off > 0; off >>= 1) {
    if (tid < off) {
      float m1 = sm[tid], s1 = ss[tid];
      float m2 = sm[tid + off], s2 = ss[tid + off];
      float M = fmaxf(m1, m2);
      sm[tid] = M;
      ss[tid] = s1 * __expf(m1 - M) + s2 * __expf(m2 - M);
    }
    __syncthreads();
  }
  if (tid == 0) {
    float lse = sm[0] + logf(ss[0]);
    float mu = (i < 1024) ? NORMC : (NORMC + LOGN);
    out[i] = mu - lse;
  }
}

__global__ __launch_bounds__(TPB) void assemble(const float* __restrict__ Z,
                                                const float* __restrict__ u,
                                                const float* __restrict__ v,
                                                float* __restrict__ out) {
  int idx = blockIdx.x * TPB + threadIdx.x;
  if (idx < 1025 * 1025) {
    int i = idx / 1025;
    int j = idx - i * 1025;
    out[idx] = Z[idx] + u[i] + v[j] + LOG_MN;
  }
}

// ---------------------------------------------------------------------------
// Host orchestration
// ---------------------------------------------------------------------------
static inline GB mkgb(const float* A, const float* B, float* C,
                      const float* bias = nullptr, const float* B2 = nullptr,
                      const float* res = nullptr, float* out2 = nullptr,
                      const float* mu = nullptr, const float* rs = nullptr) {
  GB g; g.A = A; g.B = B; g.B2 = B2; g.C = C; g.bias = bias; g.res = res;
  g.out2 = out2; g.mu = mu; g.rs = rs; return g;
}

extern "C" void kernel_launch(void* const* d_in, const int* in_sizes, int n_in,
                              void* d_out, int out_size, void* d_ws, size_t ws_size,
                              hipStream_t stream) {
  const float* kp0     = (const float*)d_in[0];
  const float* kp1     = (const float*)d_in[1];
  const float* desc0   = (const float*)d_in[2];
  const float* desc1   = (const float*)d_in[3];
  const float* sc0     = (const float*)d_in[4];
  const float* sc1     = (const float*)d_in[5];
  const float* kw[4]   = {(const float*)d_in[6], (const float*)d_in[8],
                          (const float*)d_in[10], (const float*)d_in[12]};
  const float* kb[4]   = {(const float*)d_in[7], (const float*)d_in[9],
                          (const float*)d_in[11], (const float*)d_in[13]};
  const float* proj_w  = (const float*)d_in[14];
  const float* proj_b  = (const float*)d_in[15];
  const float* merge_w = (const float*)d_in[16];
  const float* merge_b = (const float*)d_in[17];
  const float* mlp_w0  = (const float*)d_in[18];
  const float* mlp_b0  = (const float*)d_in[19];
  const float* mlp_w1  = (const float*)d_in[20];
  const float* mlp_b1  = (const float*)d_in[21];
  const float* final_w = (const float*)d_in[22];
  const float* final_b = (const float*)d_in[23];
  const float* alpha_p = (const float*)d_in[24];

  const long DSTR = 256 * 1024;           // one image of [256][1024]
  float* ws  = (float*)d_ws;
  float* dA  = ws;                        // 2*DSTR
  float* dB  = dA  + 2 * DSTR;            // 2*DSTR
  float* h0  = dB  + 2 * DSTR;            // 2*4096
  float* hb1 = h0  + 8192;                // 2*131072
  float* hb2 = hb1 + 262144;              // 2*65536 (padded)
  float* qkv = hb2 + 262144;              // 6*DSTR
  float* Sb  = qkv + 6 * DSTR;            // 8 * 1024*1024
  float* ob  = Sb  + 8388608;             // 2*DSTR
  float* msg = ob  + 2 * DSTR;            // 2*DSTR
  float* tb  = msg + 2 * DSTR;            // 2*512*1024
  float* muA = tb  + 1048576;             // 1024
  float* rsA = muA + 1024;                // 1024
  float* mdb = rsA + 1024;                // 2*DSTR
  float* Zb  = mdb + 2 * DSTR;            // 1025*1025
  float* Zt  = Zb  + 1050625;             // 1025*1025
  float* ub  = Zt  + 1050625;             // 1025
  float* vb  = ub  + 1025;                // 1025
  size_t need_bytes = (size_t)((vb + 1025) - ws) * sizeof(float);
  if (ws_size < need_bytes) return;       // insufficient scratch -> cannot run

  // ---- keypoint encoder (both images batched via grid.y) ----
  build_h0<<<dim3(4, 2), TPB, 0, stream>>>(kp0, kp1, sc0, sc1, h0);
  chanconv<true, false><<<dim3(32, 2),  TPB, 0, stream>>>(kw[0], kb[0], h0,  4096,   nullptr, nullptr, hb1, 32768,  4);
  chanconv<true, false><<<dim3(64, 2),  TPB, 0, stream>>>(kw[1], kb[1], hb1, 32768,  nullptr, nullptr, hb2, 65536,  32);
  chanconv<true, false><<<dim3(128, 2), TPB, 0, stream>>>(kw[2], kb[2], hb2, 65536,  nullptr, nullptr, hb1, 131072, 64);
  chanconv<false, true><<<dim3(256, 2), TPB, 0, stream>>>(kw[3], kb[3], hb1, 131072, desc0,   desc1,   dA,  DSTR,   128);

  // ---- GNN layers ----
  float* dc = dA;
  float* dn = dB;
  for (int i = 0; i < 18; ++i) {
    bool cross = (i & 1) != 0;
    const float* xs[2] = {dc, dc + DSTR};
    const float* ss2[2] = {cross ? xs[1] : xs[0], cross ? xs[0] : xs[1]};

    // K1: q/k/v projections, 6 batches (im,p)
    {
      GB8 gb{};
      for (int im = 0; im < 2; ++im)
        for (int p = 0; p < 3; ++p)
          gb.g[im * 3 + p] = mkgb(proj_w + (size_t)(i * 3 + p) * 65536,
                                  (p == 0 ? xs[im] : ss2[im]),
                                  qkv + (size_t)(im * 3 + p) * DSTR,
                                  proj_b + (size_t)(i * 3 + p) * 256);
      gemm<0, 0, false, false><<<dim3(16, 4, 6), TPB, 0, stream>>>(
          gb, 256, 1024, 256, 256, 1024, 1024, 0, 1.f, 0);
    }
    // K2: S = q^T k / 8 per (im, head); head h lives on channels c%4==h
    {
      GB8 gb{};
      for (int im = 0; im < 2; ++im)
        for (int h = 0; h < 4; ++h)
          gb.g[im * 4 + h] = mkgb(qkv + (size_t)(im * 3 + 0) * DSTR + h * 1024,
                                  qkv + (size_t)(im * 3 + 1) * DSTR + h * 1024,
                                  Sb + (size_t)(im * 4 + h) * 1048576);
      gemm<1, 0, false, false><<<dim3(16, 16, 8), TPB, 0, stream>>>(
          gb, 1024, 1024, 64, 4096, 4096, 1024, 0, 0.125f, 0);
    }
    // K3: softmax over m
    softmax_rows<<<8192, TPB, 0, stream>>>(Sb);
    // K4: O = V * P^T per (im, head)
    {
      GB8 gb{};
      for (int im = 0; im < 2; ++im)
        for (int h = 0; h < 4; ++h)
          gb.g[im * 4 + h] = mkgb(qkv + (size_t)(im * 3 + 2) * DSTR + h * 1024,
                                  Sb + (size_t)(im * 4 + h) * 1048576,
                                  ob + (size_t)im * DSTR + h * 1024);
      gemm<0, 1, false, false><<<dim3(16, 1, 8), TPB, 0, stream>>>(
          gb, 64, 1024, 1024, 4096, 1024, 4096, 0, 1.f, 0);
    }
    // K5: merge
    {
      GB8 gb{};
      for (int im = 0; im < 2; ++im)
        gb.g[im] = mkgb(merge_w + (size_t)i * 65536, ob + (size_t)im * DSTR,
                        msg + (size_t)im * DSTR, merge_b + (size_t)i * 256);
      gemm<0, 0, false, false><<<dim3(16, 4, 2), TPB, 0, stream>>>(
          gb, 256, 1024, 256, 256, 1024, 1024, 0, 1.f, 0);
    }
    // K6: mlp0 on concat([x, msg]) via split-B
    {
      GB8 gb{};
      for (int im = 0; im < 2; ++im)
        gb.g[im] = mkgb(mlp_w0 + (size_t)i * 262144, xs[im],
                        tb + (size_t)im * 524288, mlp_b0 + (size_t)i * 512,
                        msg + (size_t)im * DSTR);
      gemm<0, 0, true, false><<<dim3(16, 8, 2), TPB, 0, stream>>>(
          gb, 512, 1024, 512, 512, 1024, 1024, 0, 1.f, 256);
    }
    // K7: per-channel stats for instance norm
    rowstats<<<1024, TPB, 0, stream>>>(tb, muA, rsA);
    // K8: mlp1 with fused inorm+relu on B, residual add, write d_next
    {
      GB8 gb{};
      for (int im = 0; im < 2; ++im)
        gb.g[im] = mkgb(mlp_w1 + (size_t)i * 131072, tb + (size_t)im * 524288,
                        dn + (size_t)im * DSTR, mlp_b1 + (size_t)i * 256,
                        nullptr, xs[im], nullptr,
                        muA + (size_t)im * 512, rsA + (size_t)im * 512);
      gemm<0, 0, false, true><<<dim3(16, 4, 2), TPB, 0, stream>>>(
          gb, 256, 1024, 512, 512, 1024, 1024, 0, 1.f, 0);
    }
    float* tmp = dc; dc = dn; dn = tmp;
  }

  // ---- final projection ----
  {
    GB8 gb{};
    for (int im = 0; im < 2; ++im)
      gb.g[im] = mkgb(final_w, dc + (size_t)im * DSTR, mdb + (size_t)im * DSTR, final_b);
    gemm<0, 0, false, false><<<dim3(16, 4, 2), TPB, 0, stream>>>(
        gb, 256, 1024, 256, 256, 1024, 1024, 0, 1.f, 0);
  }
  // ---- scores = md0^T md1 / 16 -> Z (and Z^T) ----
  {
    GB8 gb{};
    gb.g[0] = mkgb(mdb, mdb + DSTR, Zb, nullptr, nullptr, nullptr, Zt);
    gemm<1, 0, false, false><<<dim3(16, 16, 1), TPB, 0, stream>>>(
        gb, 1024, 1024, 256, 1024, 1024, 1025, 1025, 0.0625f, 0);
  }
  fill_bins<<<5, TPB, 0, stream>>>(Zb, Zt, alpha_p);
  vinit<<<5, TPB, 0, stream>>>(vb);

  // ---- Sinkhorn: 100 iterations ----
  for (int it = 0; it < 100; ++it) {
    sink_step<<<1025, TPB, 0, stream>>>(Zb, vb, ub);   // u = log_mu - LSE_rows(Z + v)
    sink_step<<<1025, TPB, 0, stream>>>(Zt, ub, vb);   // v = log_nu - LSE_cols(Z + u)
  }

  // ---- output: Z + u + v + log(2048) ----
  assemble<<<4105, TPB, 0, stream>>>(Zb, ub, vb, (float*)d_out);
}

// Round 2
// 3847.655 us; speedup vs baseline: 1.2716x; 1.2716x over previous
//
#include <hip/hip_runtime.h>
#include <cstddef>

#define TPB 256

// ---------------------------------------------------------------------------
// block reductions (for chanconv)
// ---------------------------------------------------------------------------
__device__ __forceinline__ float block_sum(float v, float* red) {
  int tid = threadIdx.x;
  red[tid] = v; __syncthreads();
#pragma unroll
  for (int off = 128; off > 0; off >>= 1) {
    if (tid < off) red[tid] += red[tid + off];
    __syncthreads();
  }
  float r = red[0];
  __syncthreads();
  return r;
}

// ---------------------------------------------------------------------------
// h0 build: h0[im][4][1024]
// ---------------------------------------------------------------------------
__global__ __launch_bounds__(TPB) void build_h0(const float* __restrict__ kp0,
                                                const float* __restrict__ kp1,
                                                const float* __restrict__ sc0,
                                                const float* __restrict__ sc1,
                                                float* __restrict__ h0) {
  int n = blockIdx.x * TPB + threadIdx.x;
  int im = blockIdx.y;
  const float* kp = im ? kp1 : kp0;
  const float* sc = im ? sc1 : sc0;
  float* h = h0 + (size_t)im * 4096;
  h[n]        = kp[n * 3 + 0];
  h[1024 + n] = kp[n * 3 + 1];
  h[2048 + n] = kp[n * 3 + 2];
  h[3072 + n] = sc[n];
}

// ---------------------------------------------------------------------------
// kenc conv layer, float4 everywhere. One WG per (out-channel, image).
// ---------------------------------------------------------------------------
template<bool NORMRELU, bool RESID>
__global__ __launch_bounds__(TPB) void chanconv(const float* __restrict__ W,
                                                const float* __restrict__ bias,
                                                const float* __restrict__ in, long instride,
                                                const float* res0, const float* res1,
                                                float* __restrict__ out, long outstride, int C) {
  int o = blockIdx.x, im = blockIdx.y, tid = threadIdx.x;
  const float* inp = in + (long)im * instride;
  __shared__ float Ws[128];
  __shared__ float red[TPB];
  for (int c = tid; c < C; c += TPB) Ws[c] = W[(long)o * C + c];
  __syncthreads();
  float b = bias[o];
  float4 acc = {b, b, b, b};
  for (int c = 0; c < C; ++c) {
    float w = Ws[c];
    float4 v = *(const float4*)(inp + (long)c * 1024 + tid * 4);
    acc.x += w * v.x; acc.y += w * v.y; acc.z += w * v.z; acc.w += w * v.w;
  }
  float* orow = out + (long)im * outstride + (long)o * 1024;
  if (NORMRELU) {
    float s = acc.x + acc.y + acc.z + acc.w;
    float mean = block_sum(s, red) * (1.f / 1024.f);
    float dx = acc.x - mean, dy = acc.y - mean, dz = acc.z - mean, dw = acc.w - mean;
    float var = block_sum(dx * dx + dy * dy + dz * dz + dw * dw, red) * (1.f / 1024.f);
    float rstd = rsqrtf(var + 1e-5f);
    float4 o4 = {fmaxf(dx * rstd, 0.f), fmaxf(dy * rstd, 0.f),
                 fmaxf(dz * rstd, 0.f), fmaxf(dw * rstd, 0.f)};
    *(float4*)(orow + tid * 4) = o4;
  } else {
    if (RESID) {
      const float* res = im ? res1 : res0;
      float4 r = *(const float4*)(res + (long)o * 1024 + tid * 4);
      acc.x += r.x; acc.y += r.y; acc.z += r.z; acc.w += r.w;
    }
    *(float4*)(orow + tid * 4) = acc;
  }
}

// ---------------------------------------------------------------------------
// Batched tiled GEMM, BK=32, 256 threads.
//   AMODE 0: A[m][k]; AMODE 1: A[k][m]
//   BMODE 0: B[k][n]; BMODE 1: B[n][k]
//   BSPLIT 0 none; 1 concat-K (B then B2, BMODE0); 2 add (B+B2, BMODE1)
//   BFLAG  0 none; 1 inorm+relu on B per-k (mu/rs); 3 softmax-exp on A per-row
//   CS: column scale for C addressing: C[m*ldc + coff + CS*n]
// ---------------------------------------------------------------------------
struct GB {
  const float* A; const float* B; const float* B2; float* C;
  const float* bias; const float* res; float* out2;
  const float* mu; const float* rs;
  int coff; int pad;
};
struct GB8 { GB g[8]; };

template<int BM, int BN, int AMODE, int BMODE, int BSPLIT, int BFLAG, int CS>
__global__ __launch_bounds__(TPB) void gemm(GB8 gbs, int K,
                                            int lda, int ldb, int ldc, int ldc2,
                                            float alpha, int ksplit) {
  GB g = gbs.g[blockIdx.z];
  const int tid = threadIdx.x;
  const int m0 = blockIdx.y * BM, n0 = blockIdx.x * BN;
  __shared__ float As[32][BM + 4];
  __shared__ float Bs[32][BN + 4];
  constexpr int MR = BM / 16;
  constexpr int NR = BN / 16;
  const int ty = tid >> 4, tx = tid & 15;
  float acc[MR][NR] = {};

  for (int k0 = 0; k0 < K; k0 += 32) {
    // ---- stage A ----
    if (AMODE == 0) {
      const int kx = (tid & 7) * 4;
      const int myb = tid >> 3;
#pragma unroll
      for (int r = 0; r < BM / 32; ++r) {
        const int my = myb + 32 * r;
        float4 v = *(const float4*)(g.A + (long)(m0 + my) * lda + k0 + kx);
        if (BFLAG == 3) {
          float mu = g.mu[m0 + my], rs = g.rs[m0 + my];
          v.x = __expf(v.x - mu) * rs; v.y = __expf(v.y - mu) * rs;
          v.z = __expf(v.z - mu) * rs; v.w = __expf(v.w - mu) * rs;
        }
        As[kx + 0][my] = v.x; As[kx + 1][my] = v.y;
        As[kx + 2][my] = v.z; As[kx + 3][my] = v.w;
      }
    } else {
      constexpr int TXN = BM / 4;
      const int txa = (tid & (TXN - 1)) * 4;
#pragma unroll
      for (int r = 0; r < (32 * BM) / 1024; ++r) {
        const int ky = tid / TXN + r * (TPB / TXN);
        float4 v = *(const float4*)(g.A + (long)(k0 + ky) * lda + m0 + txa);
        *(float4*)&As[ky][txa] = v;
      }
    }
    // ---- stage B ----
    if (BMODE == 0) {
      constexpr int TXN = BN / 4;
      const int txb = (tid & (TXN - 1)) * 4;
#pragma unroll
      for (int r = 0; r < (32 * BN) / 1024; ++r) {
        const int ky = tid / TXN + r * (TPB / TXN);
        const int kg = k0 + ky;
        const float* bp;
        if (BSPLIT == 1) bp = (kg < ksplit) ? (g.B + (long)kg * ldb)
                                            : (g.B2 + (long)(kg - ksplit) * ldb);
        else bp = g.B + (long)kg * ldb;
        float4 v = *(const float4*)(bp + n0 + txb);
        if (BFLAG == 1) {
          float mu = g.mu[kg], rs = g.rs[kg];
          v.x = fmaxf((v.x - mu) * rs, 0.f); v.y = fmaxf((v.y - mu) * rs, 0.f);
          v.z = fmaxf((v.z - mu) * rs, 0.f); v.w = fmaxf((v.w - mu) * rs, 0.f);
        }
        *(float4*)&Bs[ky][txb] = v;
      }
    } else {
      const int kx = (tid & 7) * 4;
      const int nyb = tid >> 3;
#pragma unroll
      for (int r = 0; r < BN / 32; ++r) {
        const int ny = nyb + 32 * r;
        float4 v = *(const float4*)(g.B + (long)(n0 + ny) * ldb + k0 + kx);
        if (BSPLIT == 2) {
          float4 w = *(const float4*)(g.B2 + (long)(n0 + ny) * ldb + k0 + kx);
          v.x += w.x; v.y += w.y; v.z += w.z; v.w += w.w;
        }
        Bs[kx + 0][ny] = v.x; Bs[kx + 1][ny] = v.y;
        Bs[kx + 2][ny] = v.z; Bs[kx + 3][ny] = v.w;
      }
    }
    __syncthreads();
#pragma unroll
    for (int kk = 0; kk < 32; ++kk) {
      float a[MR], b[NR];
#pragma unroll
      for (int i = 0; i < MR; i += 4)
        *(float4*)&a[i] = *(const float4*)&As[kk][ty * MR + i];
      if (NR == 4) *(float4*)&b[0] = *(const float4*)&Bs[kk][tx * 4];
      else { float2 t = *(const float2*)&Bs[kk][tx * 2]; b[0] = t.x; b[1] = t.y; }
#pragma unroll
      for (int i = 0; i < MR; ++i)
#pragma unroll
        for (int j = 0; j < NR; ++j) acc[i][j] += a[i] * b[j];
    }
    __syncthreads();
  }

#pragma unroll
  for (int i = 0; i < MR; ++i) {
    const int m = m0 + ty * MR + i;
    const float bi = g.bias ? g.bias[m] : 0.f;
#pragma unroll
    for (int j = 0; j < NR; ++j) {
      const int n = n0 + tx * NR + j;
      float v = acc[i][j] * alpha + bi;
      long caddr = (long)m * ldc + g.coff + (long)CS * n;
      if (g.res) v += g.res[caddr];
      g.C[caddr] = v;
      if (g.out2) g.out2[(long)n * ldc2 + m] = v;
    }
  }
}

// ---------------------------------------------------------------------------
// rowlse: per row of S (1024 wide): Mrow = max, Inv = 1/sum(exp(x-M)).
// One wave per row, 4 rows per block.
// ---------------------------------------------------------------------------
__global__ __launch_bounds__(TPB) void rowlse(const float* __restrict__ S,
                                              float* __restrict__ Mrow,
                                              float* __restrict__ Inv) {
  int row = blockIdx.x * 4 + (threadIdx.x >> 6);
  int lane = threadIdx.x & 63;
  const float4* p = (const float4*)(S + (long)row * 1024);
  float4 v[4];
#pragma unroll
  for (int c = 0; c < 4; ++c) v[c] = p[lane + 64 * c];
  float m = -1e30f;
#pragma unroll
  for (int c = 0; c < 4; ++c)
    m = fmaxf(m, fmaxf(fmaxf(v[c].x, v[c].y), fmaxf(v[c].z, v[c].w)));
#pragma unroll
  for (int off = 32; off > 0; off >>= 1) m = fmaxf(m, __shfl_xor(m, off));
  float s = 0.f;
#pragma unroll
  for (int c = 0; c < 4; ++c)
    s += __expf(v[c].x - m) + __expf(v[c].y - m) + __expf(v[c].z - m) + __expf(v[c].w - m);
#pragma unroll
  for (int off = 32; off > 0; off >>= 1) s += __shfl_xor(s, off);
  if (lane == 0) { Mrow[row] = m; Inv[row] = 1.f / s; }
}

// ---------------------------------------------------------------------------
// rowstats: per row of tb (1024 rows x 1024): mean, rsqrt(var+eps).
// ---------------------------------------------------------------------------
__global__ __launch_bounds__(TPB) void rowstats2(const float* __restrict__ t,
                                                 float* __restrict__ mu,
                                                 float* __restrict__ rs) {
  int row = blockIdx.x * 4 + (threadIdx.x >> 6);
  int lane = threadIdx.x & 63;
  const float4* p = (const float4*)(t + (long)row * 1024);
  float s = 0.f, s2 = 0.f;
#pragma unroll
  for (int c = 0; c < 4; ++c) {
    float4 v = p[lane + 64 * c];
    s += v.x + v.y + v.z + v.w;
    s2 += v.x * v.x + v.y * v.y + v.z * v.z + v.w * v.w;
  }
#pragma unroll
  for (int off = 32; off > 0; off >>= 1) { s += __shfl_xor(s, off); s2 += __shfl_xor(s2, off); }
  if (lane == 0) {
    float mean = s * (1.f / 1024.f);
    mu[row] = mean;
    rs[row] = rsqrtf(s2 * (1.f / 1024.f) - mean * mean + 1e-5f);
  }
}

// ---------------------------------------------------------------------------
// Sinkhorn
// ---------------------------------------------------------------------------
#define NORMC  (-7.62461899f)   /* -log(2048) */
#define LOGN   (6.93147181f)    /* log(1024)  */
#define LOG_MN (7.62461899f)    /* log(2048)  */
#define ZLD    1028

__global__ __launch_bounds__(TPB) void fill_bins(float* __restrict__ Z,
                                                 float* __restrict__ Zt,
                                                 const float* __restrict__ alpha_p) {
  float a = *alpha_p;
  int t = blockIdx.x * TPB + threadIdx.x;
  if (t <= 1024) {
    Z[(long)t * ZLD + 1024] = a;  Z[(long)1024 * ZLD + t] = a;
    Zt[(long)t * ZLD + 1024] = a; Zt[(long)1024 * ZLD + t] = a;
#pragma unroll
    for (int j = 0; j < 3; ++j) {
      Z[(long)t * ZLD + 1025 + j] = -1e30f;
      Zt[(long)t * ZLD + 1025 + j] = -1e30f;
    }
  }
}

__global__ __launch_bounds__(TPB) void vinit(float* __restrict__ v) {
  int t = blockIdx.x * TPB + threadIdx.x;
  if (t < ZLD) v[t] = 0.f;
}

// out[row] = mu(row) - logsumexp_j( Zm[row][j] + w[j] ); one wave per row
__global__ __launch_bounds__(TPB) void sink2(const float* __restrict__ Zm,
                                             const float* __restrict__ w,
                                             float* __restrict__ out) {
  int row = blockIdx.x * 4 + (threadIdx.x >> 6);
  if (row > 1024) return;
  int lane = threadIdx.x & 63;
  const float4* zp = (const float4*)(Zm + (long)row * ZLD);
  const float4* wp = (const float4*)w;
  float m = -1e30f, s = 0.f;
#pragma unroll
  for (int c = 0; c < 5; ++c) {
    int idx = lane + 64 * c;
    if (idx < 257) {
      float4 z = zp[idx], wv = wp[idx];
      float v0 = z.x + wv.x, v1 = z.y + wv.y, v2 = z.z + wv.z, v3 = z.w + wv.w;
      float m4 = fmaxf(fmaxf(v0, v1), fmaxf(v2, v3));
      float mn = fmaxf(m, m4);
      s = s * __expf(m - mn) + __expf(v0 - mn) + __expf(v1 - mn)
        + __expf(v2 - mn) + __expf(v3 - mn);
      m = mn;
    }
  }
#pragma unroll
  for (int off = 32; off > 0; off >>= 1) {
    float mo = __shfl_xor(m, off), so = __shfl_xor(s, off);
    float mn = fmaxf(m, mo);
    s = s * __expf(m - mn) + so * __expf(mo - mn);
    m = mn;
  }
  if (lane == 0) {
    float mu = (row < 1024) ? NORMC : (NORMC + LOGN);
    out[row] = mu - (m + logf(s));
  }
}

__global__ __launch_bounds__(TPB) void assemble(const float* __restrict__ Z,
                                                const float* __restrict__ u,
                                                const float* __restrict__ v,
                                                float* __restrict__ out) {
  int idx = blockIdx.x * TPB + threadIdx.x;
  if (idx < 1025 * 1025) {
    int i = idx / 1025;
    int j = idx - i * 1025;
    out[idx] = Z[(long)i * ZLD + j] + u[i] + v[j] + LOG_MN;
  }
}

// ---------------------------------------------------------------------------
// Host orchestration
// ---------------------------------------------------------------------------
static inline GB mkgb(const float* A, const float* B, float* C,
                      const float* bias = nullptr, const float* B2 = nullptr,
                      const float* res = nullptr, float* out2 = nullptr,
                      const float* mu = nullptr, const float* rs = nullptr,
                      int coff = 0) {
  GB g; g.A = A; g.B = B; g.B2 = B2; g.C = C; g.bias = bias; g.res = res;
  g.out2 = out2; g.mu = mu; g.rs = rs; g.coff = coff; g.pad = 0; return g;
}

extern "C" void kernel_launch(void* const* d_in, const int* in_sizes, int n_in,
                              void* d_out, int out_size, void* d_ws, size_t ws_size,
                              hipStream_t stream) {
  const float* kp0     = (const float*)d_in[0];
  const float* kp1     = (const float*)d_in[1];
  const float* desc0   = (const float*)d_in[2];
  const float* desc1   = (const float*)d_in[3];
  const float* sc0     = (const float*)d_in[4];
  const float* sc1     = (const float*)d_in[5];
  const float* kw[4]   = {(const float*)d_in[6], (const float*)d_in[8],
                          (const float*)d_in[10], (const float*)d_in[12]};
  const float* kb[4]   = {(const float*)d_in[7], (const float*)d_in[9],
                          (const float*)d_in[11], (const float*)d_in[13]};
  const float* proj_w  = (const float*)d_in[14];
  const float* proj_b  = (const float*)d_in[15];
  const float* merge_w = (const float*)d_in[16];
  const float* merge_b = (const float*)d_in[17];
  const float* mlp_w0  = (const float*)d_in[18];
  const float* mlp_b0  = (const float*)d_in[19];
  const float* mlp_w1  = (const float*)d_in[20];
  const float* mlp_b1  = (const float*)d_in[21];
  const float* final_w = (const float*)d_in[22];
  const float* final_b = (const float*)d_in[23];
  const float* alpha_p = (const float*)d_in[24];

  const long DSTR = 262144;
  float* ws  = (float*)d_ws;
  float* dA  = ws;                    // 524288
  float* dB  = dA  + 524288;          // 524288
  float* h0  = dB  + 524288;          // 8192
  float* hb1 = h0  + 8192;            // 262144
  float* hb2 = hb1 + 262144;          // 131072
  float* qkv = hb2 + 131072;          // 1572864
  float* Sb  = qkv + 1572864;         // 8388608
  float* oA  = Sb  + 8388608;         // 524288
  float* oB  = oA  + 524288;          // 524288
  float* msg = oB  + 524288;          // 524288
  float* tb  = msg + 524288;          // 1048576
  float* muA = tb  + 1048576;         // 1024
  float* rsA = muA + 1024;            // 1024
  float* Mrw = rsA + 1024;            // 8192
  float* Inv = Mrw + 8192;            // 8192
  float* mdb = Inv + 8192;            // 524288
  float* Zb  = mdb + 524288;          // 1053700
  float* Zt  = Zb  + 1053700;         // 1053700
  float* ub  = Zt  + 1053700;         // 1028
  float* vb  = ub  + 1028;            // 1028
  size_t need_bytes = (size_t)((vb + 1028) - ws) * sizeof(float);
  if (ws_size < need_bytes) return;

  // ---- keypoint encoder ----
  build_h0<<<dim3(4, 2), TPB, 0, stream>>>(kp0, kp1, sc0, sc1, h0);
  chanconv<true, false><<<dim3(32, 2),  TPB, 0, stream>>>(kw[0], kb[0], h0,  4096,   nullptr, nullptr, hb1, 32768,  4);
  chanconv<true, false><<<dim3(64, 2),  TPB, 0, stream>>>(kw[1], kb[1], hb1, 32768,  nullptr, nullptr, hb2, 65536,  32);
  chanconv<true, false><<<dim3(128, 2), TPB, 0, stream>>>(kw[2], kb[2], hb2, 65536,  nullptr, nullptr, hb1, 131072, 64);
  chanconv<false, true><<<dim3(256, 2), TPB, 0, stream>>>(kw[3], kb[3], hb1, 131072, desc0,   desc1,   dA,  DSTR,   128);

  // ---- GNN layers ----
  float* dc = dA;
  float* dn = dB;
  for (int i = 0; i < 18; ++i) {
    bool cross = (i & 1) != 0;
    const float* xs[2] = {dc, dc + DSTR};
    const float* ss2[2] = {cross ? xs[1] : xs[0], cross ? xs[0] : xs[1]};

    // K1: q/k/v projections (6 batches)
    {
      GB8 gb{};
      for (int im = 0; im < 2; ++im)
        for (int p = 0; p < 3; ++p)
          gb.g[im * 3 + p] = mkgb(proj_w + (size_t)(i * 3 + p) * 65536,
                                  (p == 0 ? xs[im] : ss2[im]),
                                  qkv + (size_t)(im * 3 + p) * DSTR,
                                  proj_b + (size_t)(i * 3 + p) * 256);
      gemm<64, 64, 0, 0, 0, 0, 1><<<dim3(16, 4, 6), TPB, 0, stream>>>(
          gb, 256, 256, 1024, 1024, 0, 1.f, 0);
    }
    // K2: S = q^T k / 8  (8 batches im,h)
    {
      GB8 gb{};
      for (int im = 0; im < 2; ++im)
        for (int h = 0; h < 4; ++h)
          gb.g[im * 4 + h] = mkgb(qkv + (size_t)(im * 3 + 0) * DSTR + h * 1024,
                                  qkv + (size_t)(im * 3 + 1) * DSTR + h * 1024,
                                  Sb + (size_t)(im * 4 + h) * 1048576);
      gemm<128, 64, 1, 0, 0, 0, 1><<<dim3(16, 8, 8), TPB, 0, stream>>>(
          gb, 64, 4096, 4096, 1024, 0, 0.125f, 0);
    }
    // K3: per-row softmax stats
    rowlse<<<2048, TPB, 0, stream>>>(Sb, Mrw, Inv);
    // K4T: oT[n][c] = sum_kv P[n][kv] v[c][kv], exp fused on A; K split in 2
    for (int kh = 0; kh < 2; ++kh) {
      GB8 gb{};
      for (int imh = 0; imh < 8; ++imh) {
        int im = imh >> 2, h = imh & 3;
        gb.g[imh] = mkgb(Sb + (size_t)imh * 1048576 + kh * 512,
                         qkv + (size_t)(im * 3 + 2) * DSTR + h * 1024 + kh * 512,
                         (kh ? oB : oA) + (size_t)im * 262144,
                         nullptr, nullptr, nullptr, nullptr,
                         Mrw + imh * 1024, Inv + imh * 1024, h);
      }
      gemm<64, 64, 0, 1, 0, 3, 4><<<dim3(1, 16, 8), TPB, 0, stream>>>(
          gb, 512, 1024, 4096, 256, 0, 1.f, 0);
    }
    // K5: merge (reads oT partials, sums them)
    {
      GB8 gb{};
      for (int im = 0; im < 2; ++im)
        gb.g[im] = mkgb(merge_w + (size_t)i * 65536, oA + (size_t)im * 262144,
                        msg + (size_t)im * DSTR, merge_b + (size_t)i * 256,
                        oB + (size_t)im * 262144);
      gemm<64, 32, 0, 1, 2, 0, 1><<<dim3(32, 4, 2), TPB, 0, stream>>>(
          gb, 256, 256, 256, 1024, 0, 1.f, 0);
    }
    // K6: mlp0 on concat([x, msg])
    {
      GB8 gb{};
      for (int im = 0; im < 2; ++im)
        gb.g[im] = mkgb(mlp_w0 + (size_t)i * 262144, xs[im],
                        tb + (size_t)im * 524288, mlp_b0 + (size_t)i * 512,
                        msg + (size_t)im * DSTR);
      gemm<64, 64, 0, 0, 1, 0, 1><<<dim3(16, 8, 2), TPB, 0, stream>>>(
          gb, 512, 512, 1024, 1024, 0, 1.f, 256);
    }
    // K7: per-channel inorm stats
    rowstats2<<<256, TPB, 0, stream>>>(tb, muA, rsA);
    // K8: mlp1 with fused inorm+relu on B, residual
    {
      GB8 gb{};
      for (int im = 0; im < 2; ++im)
        gb.g[im] = mkgb(mlp_w1 + (size_t)i * 131072, tb + (size_t)im * 524288,
                        dn + (size_t)im * DSTR, mlp_b1 + (size_t)i * 256,
                        nullptr, xs[im], nullptr,
                        muA + (size_t)im * 512, rsA + (size_t)im * 512);
      gemm<64, 32, 0, 0, 0, 1, 1><<<dim3(32, 4, 2), TPB, 0, stream>>>(
          gb, 512, 512, 1024, 1024, 0, 1.f, 0);
    }
    float* tmp = dc; dc = dn; dn = tmp;
  }

  // ---- final projection ----
  {
    GB8 gb{};
    for (int im = 0; im < 2; ++im)
      gb.g[im] = mkgb(final_w, dc + (size_t)im * DSTR, mdb + (size_t)im * DSTR, final_b);
    gemm<64, 32, 0, 0, 0, 0, 1><<<dim3(32, 4, 2), TPB, 0, stream>>>(
        gb, 256, 256, 1024, 1024, 0, 1.f, 0);
  }
  // ---- scores -> Z (and Z^T), ld=1028 ----
  {
    GB8 gb{};
    gb.g[0] = mkgb(mdb, mdb + DSTR, Zb, nullptr, nullptr, nullptr, Zt);
    gemm<64, 64, 1, 0, 0, 0, 1><<<dim3(16, 16, 1), TPB, 0, stream>>>(
        gb, 256, 1024, 1024, ZLD, ZLD, 0.0625f, 0);
  }
  fill_bins<<<5, TPB, 0, stream>>>(Zb, Zt, alpha_p);
  vinit<<<5, TPB, 0, stream>>>(vb);

  // ---- Sinkhorn: 100 iterations ----
  for (int it = 0; it < 100; ++it) {
    sink2<<<257, TPB, 0, stream>>>(Zb, vb, ub);
    sink2<<<257, TPB, 0, stream>>>(Zt, ub, vb);
  }

  // ---- output ----
  assemble<<<4105, TPB, 0, stream>>>(Zb, ub, vb, (float*)d_out);
}

// Round 3
// 2119.891 us; speedup vs baseline: 2.3080x; 1.8150x over previous
//
#include <hip/hip_runtime.h>
#include <cstddef>

#define TPB 256

typedef _Float16 f16;
typedef _Float16 f16x4 __attribute__((ext_vector_type(4)));
typedef _Float16 f16x8 __attribute__((ext_vector_type(8)));
typedef float f32x4 __attribute__((ext_vector_type(4)));

// ---------------------------------------------------------------------------
// block reduction (for chanconv)
// ---------------------------------------------------------------------------
__device__ __forceinline__ float block_sum(float v, float* red) {
  int tid = threadIdx.x;
  red[tid] = v; __syncthreads();
#pragma unroll
  for (int off = 128; off > 0; off >>= 1) {
    if (tid < off) red[tid] += red[tid + off];
    __syncthreads();
  }
  float r = red[0];
  __syncthreads();
  return r;
}

// ---------------------------------------------------------------------------
// h0 build: h0[im][4][1024]
// ---------------------------------------------------------------------------
__global__ __launch_bounds__(TPB) void build_h0(const float* __restrict__ kp0,
                                                const float* __restrict__ kp1,
                                                const float* __restrict__ sc0,
                                                const float* __restrict__ sc1,
                                                float* __restrict__ h0) {
  int n = blockIdx.x * TPB + threadIdx.x;
  int im = blockIdx.y;
  const float* kp = im ? kp1 : kp0;
  const float* sc = im ? sc1 : sc0;
  float* h = h0 + (size_t)im * 4096;
  h[n]        = kp[n * 3 + 0];
  h[1024 + n] = kp[n * 3 + 1];
  h[2048 + n] = kp[n * 3 + 2];
  h[3072 + n] = sc[n];
}

// ---------------------------------------------------------------------------
// kenc conv layer (fp32, small)
// ---------------------------------------------------------------------------
template<bool NORMRELU, bool RESID>
__global__ __launch_bounds__(TPB) void chanconv(const float* __restrict__ W,
                                                const float* __restrict__ bias,
                                                const float* __restrict__ in, long instride,
                                                const float* res0, const float* res1,
                                                float* __restrict__ out, long outstride, int C) {
  int o = blockIdx.x, im = blockIdx.y, tid = threadIdx.x;
  const float* inp = in + (long)im * instride;
  __shared__ float Ws[128];
  __shared__ float red[TPB];
  for (int c = tid; c < C; c += TPB) Ws[c] = W[(long)o * C + c];
  __syncthreads();
  float b = bias[o];
  float4 acc = {b, b, b, b};
  for (int c = 0; c < C; ++c) {
    float w = Ws[c];
    float4 v = *(const float4*)(inp + (long)c * 1024 + tid * 4);
    acc.x += w * v.x; acc.y += w * v.y; acc.z += w * v.z; acc.w += w * v.w;
  }
  float* orow = out + (long)im * outstride + (long)o * 1024;
  if (NORMRELU) {
    float s = acc.x + acc.y + acc.z + acc.w;
    float mean = block_sum(s, red) * (1.f / 1024.f);
    float dx = acc.x - mean, dy = acc.y - mean, dz = acc.z - mean, dw = acc.w - mean;
    float var = block_sum(dx * dx + dy * dy + dz * dz + dw * dw, red) * (1.f / 1024.f);
    float rstd = rsqrtf(var + 1e-5f);
    float4 o4 = {fmaxf(dx * rstd, 0.f), fmaxf(dy * rstd, 0.f),
                 fmaxf(dz * rstd, 0.f), fmaxf(dw * rstd, 0.f)};
    *(float4*)(orow + tid * 4) = o4;
  } else {
    if (RESID) {
      const float* res = im ? res1 : res0;
      float4 r = *(const float4*)(res + (long)o * 1024 + tid * 4);
      acc.x += r.x; acc.y += r.y; acc.z += r.z; acc.w += r.w;
    }
    *(float4*)(orow + tid * 4) = acc;
  }
}

// ---------------------------------------------------------------------------
// fp16-MFMA batched GEMM. Block 64xBN, 4 waves (2x2), wave 32x(BN/2).
// MFMA v_mfma_f32_16x16x16_f16; A-frag lane l: row=l&15, k=4*(l>>4)+j;
// B-frag: col=l&15, same k; D: col=l&15, row=4*(l>>4)+reg.
// LDS: As[m][k] / Bs[n][k] with k-contiguous rows, pitch 36 f16.
//   ASRC 0: fp32 [m][k]   1: f16 [k][m]   2: f16 [m][k] + softmax exp (mu=M, rs=inv)
//   BSRC 0: fp32 [k][n] (+concat B2)   1: f16 [k][n] (+inorm-relu)   2: f16 [n][k] (+add B2)
// FLAGS: 1 BNORM, 2 BCONCAT, 4 BADD, 8 CD16-out, 16 RES(fp32), 32 OUT2(sink triple), 64 CSCAT
// ---------------------------------------------------------------------------
struct GBH {
  const void* A; const void* B; const void* B2; void* C;
  const float* bias; const float* res; const float* mu; const float* rs;
  void* o2a; void* o2b; int coff; int pad;
};
struct GB16 { GBH g[16]; };

#define F_BNORM   1
#define F_BCONCAT 2
#define F_BADD    4
#define F_CD16    8
#define F_RES     16
#define F_OUT2    32
#define F_CSCAT   64

template<int BN, int ASRC, int BSRC, int FLAGS>
__global__ __launch_bounds__(TPB) void gemmh(GB16 gbs, int K, int lda, int ldb,
                                             int ldc, float alpha, int ksplit) {
  constexpr int WN = BN / 2;
  constexpr int NFR = WN / 16;
  GBH g = gbs.g[blockIdx.z];
  const int tid = threadIdx.x;
  const int lane = tid & 63, wid = tid >> 6;
  const int wm = wid >> 1, wn = wid & 1;
  const int m0 = blockIdx.y * 64, n0 = blockIdx.x * BN;
  __shared__ f16 As[64][36];
  __shared__ f16 Bs[BN][36];
  f32x4 acc[2][NFR];
#pragma unroll
  for (int i = 0; i < 2; ++i)
#pragma unroll
    for (int j = 0; j < NFR; ++j) acc[i][j] = (f32x4){0.f, 0.f, 0.f, 0.f};

  for (int k0 = 0; k0 < K; k0 += 32) {
    // ---- stage A ----
    if constexpr (ASRC == 0) {
      const int m = tid >> 2, k4 = (tid & 3) * 8;
      const float* ap = (const float*)g.A + (long)(m0 + m) * lda + k0 + k4;
      float4 u0 = *(const float4*)ap, u1 = *(const float4*)(ap + 4);
      f16x4 h0 = {(f16)u0.x, (f16)u0.y, (f16)u0.z, (f16)u0.w};
      f16x4 h1 = {(f16)u1.x, (f16)u1.y, (f16)u1.z, (f16)u1.w};
      *(f16x4*)&As[m][k4] = h0;
      *(f16x4*)&As[m][k4 + 4] = h1;
    } else if constexpr (ASRC == 1) {
      const int k = tid >> 3, mg = (tid & 7) * 8;
      const f16* ap = (const f16*)g.A + (long)(k0 + k) * lda + m0 + mg;
      f16x8 h = *(const f16x8*)ap;
#pragma unroll
      for (int j = 0; j < 8; ++j) As[mg + j][k] = h[j];
    } else {
      const int m = tid >> 2, k4 = (tid & 3) * 8;
      const f16* ap = (const f16*)g.A + (long)(m0 + m) * lda + k0 + k4;
      f16x8 h = *(const f16x8*)ap;
      const float M = g.mu[m0 + m], Iv = g.rs[m0 + m];
      f16x4 h0, h1;
#pragma unroll
      for (int j = 0; j < 4; ++j) h0[j] = (f16)(__expf((float)h[j] - M) * Iv);
#pragma unroll
      for (int j = 0; j < 4; ++j) h1[j] = (f16)(__expf((float)h[j + 4] - M) * Iv);
      *(f16x4*)&As[m][k4] = h0;
      *(f16x4*)&As[m][k4 + 4] = h1;
    }
    // ---- stage B ----
#pragma unroll
    for (int r = 0; r < BN / 64; ++r) {
      if constexpr (BSRC == 0) {
        const int k = tid >> 3, ng = (tid & 7) * 8 + r * 64;
        const int kg = k0 + k;
        const float* bp;
        if constexpr ((FLAGS & F_BCONCAT) != 0)
          bp = (kg < ksplit) ? ((const float*)g.B + (long)kg * ldb)
                             : ((const float*)g.B2 + (long)(kg - ksplit) * ldb);
        else
          bp = (const float*)g.B + (long)kg * ldb;
        float4 u0 = *(const float4*)(bp + n0 + ng);
        float4 u1 = *(const float4*)(bp + n0 + ng + 4);
        Bs[ng + 0][k] = (f16)u0.x; Bs[ng + 1][k] = (f16)u0.y;
        Bs[ng + 2][k] = (f16)u0.z; Bs[ng + 3][k] = (f16)u0.w;
        Bs[ng + 4][k] = (f16)u1.x; Bs[ng + 5][k] = (f16)u1.y;
        Bs[ng + 6][k] = (f16)u1.z; Bs[ng + 7][k] = (f16)u1.w;
      } else if constexpr (BSRC == 1) {
        const int k = tid >> 3, ng = (tid & 7) * 8 + r * 64;
        const int kg = k0 + k;
        f16x8 h = *(const f16x8*)((const f16*)g.B + (long)kg * ldb + n0 + ng);
        if constexpr ((FLAGS & F_BNORM) != 0) {
          const float mu = g.mu[kg], rs = g.rs[kg];
#pragma unroll
          for (int j = 0; j < 8; ++j)
            h[j] = (f16)fmaxf(((float)h[j] - mu) * rs, 0.f);
        }
#pragma unroll
        for (int j = 0; j < 8; ++j) Bs[ng + j][k] = h[j];
      } else {
        const int n = (tid >> 2) + r * 64, k4 = (tid & 3) * 8;
        const f16* bp = (const f16*)g.B + (long)(n0 + n) * ldb + k0 + k4;
        f16x8 h = *(const f16x8*)bp;
        if constexpr ((FLAGS & F_BADD) != 0) {
          f16x8 h2 = *(const f16x8*)((const f16*)g.B2 + (long)(n0 + n) * ldb + k0 + k4);
          h = h + h2;
        }
        f16x4 h0 = {h[0], h[1], h[2], h[3]};
        f16x4 h1 = {h[4], h[5], h[6], h[7]};
        *(f16x4*)&Bs[n][k4] = h0;
        *(f16x4*)&Bs[n][k4 + 4] = h1;
      }
    }
    __syncthreads();
    // ---- MFMA ----
#pragma unroll
    for (int ks = 0; ks < 2; ++ks) {
      const int kof = ks * 16 + ((lane >> 4) << 2);
      f16x4 a[2], b[NFR];
      a[0] = *(const f16x4*)&As[wm * 32 + (lane & 15)][kof];
      a[1] = *(const f16x4*)&As[wm * 32 + 16 + (lane & 15)][kof];
#pragma unroll
      for (int fn = 0; fn < NFR; ++fn)
        b[fn] = *(const f16x4*)&Bs[wn * WN + fn * 16 + (lane & 15)][kof];
#pragma unroll
      for (int fm = 0; fm < 2; ++fm)
#pragma unroll
        for (int fn = 0; fn < NFR; ++fn)
          acc[fm][fn] = __builtin_amdgcn_mfma_f32_16x16x16f16(a[fm], b[fn], acc[fm][fn], 0, 0, 0);
    }
    __syncthreads();
  }

  // ---- epilogue ----
  const int r0 = (lane >> 4) << 2, cn = lane & 15;
#pragma unroll
  for (int fm = 0; fm < 2; ++fm) {
#pragma unroll
    for (int r = 0; r < 4; ++r) {
      const int m = m0 + wm * 32 + fm * 16 + r0 + r;
      const float bi = g.bias ? g.bias[m] : 0.f;
#pragma unroll
      for (int fn = 0; fn < NFR; ++fn) {
        const int n = n0 + wn * WN + fn * 16 + cn;
        float v = acc[fm][fn][r] * alpha + bi;
        if constexpr ((FLAGS & F_RES) != 0) v += g.res[(long)m * ldc + n];
        if constexpr ((FLAGS & F_OUT2) != 0) {
          ((float*)g.C)[(long)m * 1028 + n] = v;
          ((f16*)g.o2a)[(long)m * 1028 + n] = (f16)v;
          ((f16*)g.o2b)[(long)n * 1028 + m] = (f16)v;
        } else if constexpr ((FLAGS & F_CSCAT) != 0) {
          ((f16*)g.C)[(long)m * ldc + g.coff + 4 * n] = (f16)v;
        } else if constexpr ((FLAGS & F_CD16) != 0) {
          ((f16*)g.C)[(long)m * ldc + n] = (f16)v;
        } else {
          ((float*)g.C)[(long)m * ldc + n] = v;
        }
      }
    }
  }
}

// ---------------------------------------------------------------------------
// rowlse over f16 S rows (1024 wide): Mrow, Inv = 1/sum(exp(x-M)). Wave/row.
// ---------------------------------------------------------------------------
__global__ __launch_bounds__(TPB) void rowlse_h(const f16* __restrict__ S,
                                                float* __restrict__ Mrow,
                                                float* __restrict__ Inv) {
  int row = blockIdx.x * 4 + (threadIdx.x >> 6);
  int lane = threadIdx.x & 63;
  const f16x8* p = (const f16x8*)(S + (long)row * 1024);
  f16x8 v0 = p[lane], v1 = p[lane + 64];
  float m = -1e30f;
#pragma unroll
  for (int j = 0; j < 8; ++j)
    m = fmaxf(m, fmaxf((float)v0[j], (float)v1[j]));
#pragma unroll
  for (int off = 32; off > 0; off >>= 1) m = fmaxf(m, __shfl_xor(m, off));
  float s = 0.f;
#pragma unroll
  for (int j = 0; j < 8; ++j)
    s += __expf((float)v0[j] - m) + __expf((float)v1[j] - m);
#pragma unroll
  for (int off = 32; off > 0; off >>= 1) s += __shfl_xor(s, off);
  if (lane == 0) { Mrow[row] = m; Inv[row] = 1.f / s; }
}

// ---------------------------------------------------------------------------
// rowstats over f16 tb rows (1024 wide): mean, rsqrt(var+eps). Wave/row.
// ---------------------------------------------------------------------------
__global__ __launch_bounds__(TPB) void rowstats2_h(const f16* __restrict__ t,
                                                   float* __restrict__ mu,
                                                   float* __restrict__ rs) {
  int row = blockIdx.x * 4 + (threadIdx.x >> 6);
  int lane = threadIdx.x & 63;
  const f16x8* p = (const f16x8*)(t + (long)row * 1024);
  f16x8 v0 = p[lane], v1 = p[lane + 64];
  float s = 0.f, s2 = 0.f;
#pragma unroll
  for (int j = 0; j < 8; ++j) {
    float a = (float)v0[j], b = (float)v1[j];
    s += a + b; s2 += a * a + b * b;
  }
#pragma unroll
  for (int off = 32; off > 0; off >>= 1) { s += __shfl_xor(s, off); s2 += __shfl_xor(s2, off); }
  if (lane == 0) {
    float mean = s * (1.f / 1024.f);
    mu[row] = mean;
    rs[row] = rsqrtf(fmaxf(s2 * (1.f / 1024.f) - mean * mean, 0.f) + 1e-5f);
  }
}

// ---------------------------------------------------------------------------
// Sinkhorn
// ---------------------------------------------------------------------------
#define NORMC  (-7.62461899f)   /* -log(2048) */
#define LOGN   (6.93147181f)    /* log(1024)  */
#define LOG_MN (7.62461899f)    /* log(2048)  */
#define ZLD    1028

__global__ __launch_bounds__(TPB) void fill_bins(float* __restrict__ Z,
                                                 f16* __restrict__ Zh,
                                                 f16* __restrict__ Zth,
                                                 const float* __restrict__ alpha_p) {
  float a = *alpha_p;
  int t = blockIdx.x * TPB + threadIdx.x;
  if (t <= 1024) {
    Z[(long)t * ZLD + 1024] = a;
    Z[(long)1024 * ZLD + t] = a;
    Zh[(long)t * ZLD + 1024] = (f16)a;
    Zh[(long)1024 * ZLD + t] = (f16)a;
    Zth[(long)t * ZLD + 1024] = (f16)a;
    Zth[(long)1024 * ZLD + t] = (f16)a;
#pragma unroll
    for (int j = 0; j < 3; ++j) {
      Zh[(long)t * ZLD + 1025 + j] = (f16)(-1e30f);
      Zth[(long)t * ZLD + 1025 + j] = (f16)(-1e30f);
    }
  }
}

__global__ __launch_bounds__(TPB) void vinit(float* __restrict__ v) {
  int t = blockIdx.x * TPB + threadIdx.x;
  if (t < ZLD) v[t] = 0.f;
}

// out[row] = mu(row) - logsumexp_j( Zm[row][j] + w[j] ); one wave per row
__global__ __launch_bounds__(TPB) void sink2h(const f16* __restrict__ Zm,
                                              const float* __restrict__ w,
                                              float* __restrict__ out) {
  int row = blockIdx.x * 4 + (threadIdx.x >> 6);
  if (row > 1024) return;
  int lane = threadIdx.x & 63;
  const f16x4* zp = (const f16x4*)(Zm + (long)row * ZLD);
  const float4* wp = (const float4*)w;
  float m = -1e30f, s = 0.f;
#pragma unroll
  for (int c = 0; c < 5; ++c) {
    int idx = lane + 64 * c;
    if (idx < 257) {
      f16x4 z = zp[idx];
      float4 wv = wp[idx];
      float v0 = (float)z[0] + wv.x, v1 = (float)z[1] + wv.y;
      float v2 = (float)z[2] + wv.z, v3 = (float)z[3] + wv.w;
      float m4 = fmaxf(fmaxf(v0, v1), fmaxf(v2, v3));
      float mn = fmaxf(m, m4);
      s = s * __expf(m - mn) + __expf(v0 - mn) + __expf(v1 - mn)
        + __expf(v2 - mn) + __expf(v3 - mn);
      m = mn;
    }
  }
#pragma unroll
  for (int off = 32; off > 0; off >>= 1) {
    float mo = __shfl_xor(m, off), so = __shfl_xor(s, off);
    float mn = fmaxf(m, mo);
    s = s * __expf(m - mn) + so * __expf(mo - mn);
    m = mn;
  }
  if (lane == 0) {
    float mu = (row < 1024) ? NORMC : (NORMC + LOGN);
    out[row] = mu - (m + logf(s));
  }
}

__global__ __launch_bounds__(TPB) void assemble(const float* __restrict__ Z,
                                                const float* __restrict__ u,
                                                const float* __restrict__ v,
                                                float* __restrict__ out) {
  int idx = blockIdx.x * TPB + threadIdx.x;
  if (idx < 1025 * 1025) {
    int i = idx / 1025;
    int j = idx - i * 1025;
    out[idx] = Z[(long)i * ZLD + j] + u[i] + v[j] + LOG_MN;
  }
}

// ---------------------------------------------------------------------------
// Host orchestration
// ---------------------------------------------------------------------------
static inline GBH mkgb(const void* A, const void* B, void* C,
                       const float* bias = nullptr, const void* B2 = nullptr,
                       const float* res = nullptr,
                       const float* mu = nullptr, const float* rs = nullptr,
                       int coff = 0, void* o2a = nullptr, void* o2b = nullptr) {
  GBH g; g.A = A; g.B = B; g.B2 = B2; g.C = C; g.bias = bias; g.res = res;
  g.mu = mu; g.rs = rs; g.o2a = o2a; g.o2b = o2b; g.coff = coff; g.pad = 0;
  return g;
}

extern "C" void kernel_launch(void* const* d_in, const int* in_sizes, int n_in,
                              void* d_out, int out_size, void* d_ws, size_t ws_size,
                              hipStream_t stream) {
  const float* kp0     = (const float*)d_in[0];
  const float* kp1     = (const float*)d_in[1];
  const float* desc0   = (const float*)d_in[2];
  const float* desc1   = (const float*)d_in[3];
  const float* sc0     = (const float*)d_in[4];
  const float* sc1     = (const float*)d_in[5];
  const float* kw[4]   = {(const float*)d_in[6], (const float*)d_in[8],
                          (const float*)d_in[10], (const float*)d_in[12]};
  const float* kb[4]   = {(const float*)d_in[7], (const float*)d_in[9],
                          (const float*)d_in[11], (const float*)d_in[13]};
  const float* proj_w  = (const float*)d_in[14];
  const float* proj_b  = (const float*)d_in[15];
  const float* merge_w = (const float*)d_in[16];
  const float* merge_b = (const float*)d_in[17];
  const float* mlp_w0  = (const float*)d_in[18];
  const float* mlp_b0  = (const float*)d_in[19];
  const float* mlp_w1  = (const float*)d_in[20];
  const float* mlp_b1  = (const float*)d_in[21];
  const float* final_w = (const float*)d_in[22];
  const float* final_b = (const float*)d_in[23];
  const float* alpha_p = (const float*)d_in[24];

  float* p = (float*)d_ws;
  float* dA  = p; p += 524288;
  float* dB  = p; p += 524288;
  float* h0  = p; p += 8192;
  float* hb1 = p; p += 262144;
  float* hb2 = p; p += 131072;
  float* msg = p; p += 524288;
  float* muA = p; p += 1024;
  float* rsA = p; p += 1024;
  float* Mrw = p; p += 8192;
  float* Inv = p; p += 8192;
  float* Zb  = p; p += 1053700;
  float* ub  = p; p += 1028;
  float* vb  = p; p += 1028;
  f16* qkvh = (f16*)p; p += 786432;   // 6 x 256 x 1024 f16
  f16* Sh   = (f16*)p; p += 4194304;  // 8 x 1024 x 1024 f16
  f16* oAh  = (f16*)p; p += 262144;   // 2 x 1024 x 256 f16
  f16* oBh  = (f16*)p; p += 262144;
  f16* tbh  = (f16*)p; p += 524288;   // 2 x 512 x 1024 f16
  f16* mdbh = (f16*)p; p += 262144;   // 2 x 256 x 1024 f16
  f16* Zh   = (f16*)p; p += 526852;
  f16* Zth  = (f16*)p; p += 526852;
  size_t need_bytes = (size_t)(p - (float*)d_ws) * sizeof(float);
  if (ws_size < need_bytes) return;

  const long DSTR = 262144;

  // ---- keypoint encoder ----
  build_h0<<<dim3(4, 2), TPB, 0, stream>>>(kp0, kp1, sc0, sc1, h0);
  chanconv<true, false><<<dim3(32, 2),  TPB, 0, stream>>>(kw[0], kb[0], h0,  4096,   nullptr, nullptr, hb1, 32768,  4);
  chanconv<true, false><<<dim3(64, 2),  TPB, 0, stream>>>(kw[1], kb[1], hb1, 32768,  nullptr, nullptr, hb2, 65536,  32);
  chanconv<true, false><<<dim3(128, 2), TPB, 0, stream>>>(kw[2], kb[2], hb2, 65536,  nullptr, nullptr, hb1, 131072, 64);
  chanconv<false, true><<<dim3(256, 2), TPB, 0, stream>>>(kw[3], kb[3], hb1, 131072, desc0,   desc1,   dA,  DSTR,   128);

  // ---- GNN layers ----
  float* dc = dA;
  float* dn = dB;
  for (int i = 0; i < 18; ++i) {
    bool cross = (i & 1) != 0;
    const float* xs[2] = {dc, dc + DSTR};
    const float* ss2[2] = {cross ? xs[1] : xs[0], cross ? xs[0] : xs[1]};

    // K1: q/k/v projections -> qkvh f16
    {
      GB16 gb{};
      for (int im = 0; im < 2; ++im)
        for (int pp = 0; pp < 3; ++pp)
          gb.g[im * 3 + pp] = mkgb(proj_w + (size_t)(i * 3 + pp) * 65536,
                                   (pp == 0 ? xs[im] : ss2[im]),
                                   qkvh + (size_t)(im * 3 + pp) * DSTR,
                                   proj_b + (size_t)(i * 3 + pp) * 256);
      gemmh<128, 0, 0, F_CD16><<<dim3(8, 4, 6), TPB, 0, stream>>>(
          gb, 256, 256, 1024, 1024, 1.f, 0);
    }
    // K2: S = q^T k / 8 -> Sh f16
    {
      GB16 gb{};
      for (int im = 0; im < 2; ++im)
        for (int h = 0; h < 4; ++h)
          gb.g[im * 4 + h] = mkgb(qkvh + (size_t)(im * 3 + 0) * DSTR + h * 1024,
                                  qkvh + (size_t)(im * 3 + 1) * DSTR + h * 1024,
                                  Sh + (size_t)(im * 4 + h) * 1048576);
      gemmh<128, 1, 1, F_CD16><<<dim3(8, 16, 8), TPB, 0, stream>>>(
          gb, 64, 4096, 4096, 1024, 0.125f, 0);
    }
    // K3: per-row softmax stats
    rowlse_h<<<2048, TPB, 0, stream>>>(Sh, Mrw, Inv);
    // K4T: oT[pos][4*d+h] = sum_kv P * v ; K split in halves -> oAh/oBh
    {
      GB16 gb{};
      for (int kh = 0; kh < 2; ++kh)
        for (int imh = 0; imh < 8; ++imh) {
          int im = imh >> 2, h = imh & 3;
          gb.g[kh * 8 + imh] = mkgb(Sh + (size_t)imh * 1048576 + kh * 512,
                                    qkvh + (size_t)(im * 3 + 2) * DSTR + h * 1024 + kh * 512,
                                    (kh ? oBh : oAh) + (size_t)im * 262144,
                                    nullptr, nullptr, nullptr,
                                    Mrw + imh * 1024, Inv + imh * 1024, h);
        }
      gemmh<64, 2, 2, F_CD16 | F_CSCAT><<<dim3(1, 16, 16), TPB, 0, stream>>>(
          gb, 512, 1024, 4096, 256, 1.f, 0);
    }
    // K5: merge (adds the two K-half partials) -> msg fp32
    {
      GB16 gb{};
      for (int im = 0; im < 2; ++im)
        gb.g[im] = mkgb(merge_w + (size_t)i * 65536, oAh + (size_t)im * 262144,
                        msg + (size_t)im * DSTR, merge_b + (size_t)i * 256,
                        oBh + (size_t)im * 262144);
      gemmh<64, 0, 2, F_BADD><<<dim3(16, 4, 2), TPB, 0, stream>>>(
          gb, 256, 256, 256, 1024, 1.f, 0);
    }
    // K6: mlp0 on concat([x, msg]) -> tbh f16
    {
      GB16 gb{};
      for (int im = 0; im < 2; ++im)
        gb.g[im] = mkgb(mlp_w0 + (size_t)i * 262144, xs[im],
                        tbh + (size_t)im * 524288, mlp_b0 + (size_t)i * 512,
                        msg + (size_t)im * DSTR);
      gemmh<64, 0, 0, F_BCONCAT | F_CD16><<<dim3(16, 8, 2), TPB, 0, stream>>>(
          gb, 512, 512, 1024, 1024, 1.f, 256);
    }
    // K7: per-channel inorm stats
    rowstats2_h<<<256, TPB, 0, stream>>>(tbh, muA, rsA);
    // K8: mlp1 with fused inorm+relu on B, fp32 residual -> dn
    {
      GB16 gb{};
      for (int im = 0; im < 2; ++im)
        gb.g[im] = mkgb(mlp_w1 + (size_t)i * 131072, tbh + (size_t)im * 524288,
                        dn + (size_t)im * DSTR, mlp_b1 + (size_t)i * 256,
                        nullptr, xs[im],
                        muA + (size_t)im * 512, rsA + (size_t)im * 512);
      gemmh<64, 0, 1, F_BNORM | F_RES><<<dim3(16, 4, 2), TPB, 0, stream>>>(
          gb, 512, 512, 1024, 1024, 1.f, 0);
    }
    float* tmp = dc; dc = dn; dn = tmp;
  }

  // ---- final projection -> mdbh f16 ----
  {
    GB16 gb{};
    for (int im = 0; im < 2; ++im)
      gb.g[im] = mkgb(final_w, dc + (size_t)im * DSTR, mdbh + (size_t)im * 262144,
                      final_b);
    gemmh<64, 0, 0, F_CD16><<<dim3(16, 4, 2), TPB, 0, stream>>>(
        gb, 256, 256, 1024, 1024, 1.f, 0);
  }
  // ---- scores -> Zb fp32 + Zh/Zth f16 ----
  {
    GB16 gb{};
    gb.g[0] = mkgb(mdbh, mdbh + 262144, Zb, nullptr, nullptr, nullptr,
                   nullptr, nullptr, 0, Zh, Zth);
    gemmh<64, 1, 1, F_OUT2><<<dim3(16, 16, 1), TPB, 0, stream>>>(
        gb, 256, 1024, 1024, ZLD, 0.0625f, 0);
  }
  fill_bins<<<5, TPB, 0, stream>>>(Zb, Zh, Zth, alpha_p);
  vinit<<<5, TPB, 0, stream>>>(vb);

  // ---- Sinkhorn: 100 iterations on f16 Z ----
  for (int it = 0; it < 100; ++it) {
    sink2h<<<257, TPB, 0, stream>>>(Zh, vb, ub);
    sink2h<<<257, TPB, 0, stream>>>(Zth, ub, vb);
  }

  // ---- output ----
  assemble<<<4105, TPB, 0, stream>>>(Zb, ub, vb, (float*)d_out);
}